// Round 4
// baseline (193.881 us; speedup 1.0000x reference)
//
#include <hip/hip_runtime.h>
#include <hip/hip_bf16.h>

#define Bb 4
#define Ss 512
#define Hh 768
#define Dd 24
#define Mm 96
#define Oo 768

typedef __bf16 bf16x8 __attribute__((ext_vector_type(8)));
typedef __bf16 bf16x4 __attribute__((ext_vector_type(4)));
typedef float f32x4 __attribute__((ext_vector_type(4)));

// ---------------------------------------------------------------------------
// Transpose tile: dst[c][r] = bf16(src[r][c]), one 32x32 tile, 8B stores.
// ---------------------------------------------------------------------------
__device__ __forceinline__ void transpose_tile_v(
    const float* __restrict__ s, __bf16* __restrict__ d,
    int R, int C, int bx, int by, float* smem, int tid)
{
    // smem used as t[32][33]
    const int x = tid & 31, y = tid >> 5;
    const int c0 = bx * 32, r0 = by * 32;
    #pragma unroll
    for (int i = 0; i < 4; ++i)
        smem[(y + 8 * i) * 33 + x] = s[(size_t)(r0 + y + 8 * i) * C + c0 + x];
    __syncthreads();
    const int cl = tid >> 3, rg = tid & 7;     // 32 cols x 8 row-groups
    bf16x4 o = { (__bf16)smem[(rg * 4 + 0) * 33 + cl],
                 (__bf16)smem[(rg * 4 + 1) * 33 + cl],
                 (__bf16)smem[(rg * 4 + 2) * 33 + cl],
                 (__bf16)smem[(rg * 4 + 3) * 33 + cl] };
    *(bf16x4*)&d[(size_t)(c0 + cl) * R + r0 + rg * 4] = o;
}

// ---------------------------------------------------------------------------
// prep_a: blocks:
//  [0,512)     proj: 8 rows/block (bid<256: Hj + Acat seg1 emit;
//              bid>=256: Hi + HiT emit). Bit-identical Z math.
//  [512,2240)  Wv1T transpose (24x72 tiles)
//  [2240,2816) Wv2T transpose (24x24 tiles)
// ---------------------------------------------------------------------------
__global__ __launch_bounds__(256) void prep_a(
    const float* __restrict__ Hj, const float* __restrict__ Hi,
    const float* __restrict__ Wpj, const float* __restrict__ Wpi,
    const float* __restrict__ Wv1, const float* __restrict__ Wv2,
    float* __restrict__ Zj_pad, float* __restrict__ Zi_pad,
    __bf16* __restrict__ Zi_pack,
    __bf16* __restrict__ HiT, __bf16* __restrict__ Wv1T,
    __bf16* __restrict__ Wv2T, __bf16* __restrict__ Acat)
{
    __shared__ float smem[7744];   // proj: rowbuf 6144 + partial [8][8][25]
    const int bid = blockIdx.x;
    const int tid = threadIdx.x;

    if (bid < 512) {
        const int which = bid >> 8;               // 0 = j, 1 = i
        const int rowbase = (bid & 255) * 8;
        const float* src = (which ? Hi : Hj) + (size_t)rowbase * Hh;
        const float* W = which ? Wpi : Wpj;
        f32x4* rowbuf4 = (f32x4*)smem;            // [1536] = 8 rows x 192
        float* partial = smem + 6144;             // [8][8][25]

        // ---- stage 8 rows (24 KB), linear float4 copy, conflict-free
        #pragma unroll
        for (int k2 = 0; k2 < 6; ++k2) {
            const int f = tid + 256 * k2;
            rowbuf4[f] = ((const f32x4*)src)[f];
        }
        __syncthreads();

        // ---- secondary emit straight from LDS
        if (which == 0) {
            #pragma unroll
            for (int k2 = 0; k2 < 6; ++k2) {
                const int f = tid + 256 * k2;
                const int r = f / 192, kk = f % 192;
                const f32x4 v = rowbuf4[f];
                bf16x4 o = {(__bf16)v[0], (__bf16)v[1], (__bf16)v[2], (__bf16)v[3]};
                *(bf16x4*)&Acat[(size_t)(rowbase + r) * 2304 + Hh + kk * 4] = o;
            }
        } else {
            const int bz = rowbase >> 9, q0 = rowbase & 511;
            __bf16* hb = HiT + (size_t)bz * Hh * Ss + q0;
            #pragma unroll
            for (int k2 = 0; k2 < 3; ++k2) {
                const int h = tid + 256 * k2;
                bf16x8 o;
                #pragma unroll
                for (int r = 0; r < 8; ++r) o[r] = (__bf16)smem[r * Hh + h];
                *(bf16x8*)&hb[(size_t)h * Ss] = o;
            }
        }

        // ---- proj compute: thread = (d, K-eighth e); 8 rows per thread
        if (tid < 192) {
            const int d = tid % Dd, e = tid / Dd;
            float acc[8];
            #pragma unroll
            for (int r = 0; r < 8; ++r) acc[r] = 0.f;
            const float* Wb = W + (size_t)(e * 96) * Dd + d;
            const f32x4* rb = rowbuf4 + e * 24;
            #pragma unroll 4
            for (int h4 = 0; h4 < 24; ++h4) {
                const float w0 = Wb[(h4 * 4 + 0) * Dd];
                const float w1 = Wb[(h4 * 4 + 1) * Dd];
                const float w2 = Wb[(h4 * 4 + 2) * Dd];
                const float w3 = Wb[(h4 * 4 + 3) * Dd];
                #pragma unroll
                for (int r = 0; r < 8; ++r) {
                    const f32x4 v = rb[r * 192 + h4];
                    acc[r] = fmaf(v[0], w0, acc[r]);
                    acc[r] = fmaf(v[1], w1, acc[r]);
                    acc[r] = fmaf(v[2], w2, acc[r]);
                    acc[r] = fmaf(v[3], w3, acc[r]);
                }
            }
            #pragma unroll
            for (int r = 0; r < 8; ++r) partial[e * 200 + r * 25 + d] = acc[r];
        }
        __syncthreads();
        if (tid < 192) {
            const int r = tid / Dd, d = tid % Dd;
            float z = 0.f;
            #pragma unroll
            for (int e = 0; e < 8; ++e) z += partial[e * 200 + r * 25 + d];
            const int row = rowbase + r;
            (which ? Zi_pad : Zj_pad)[(size_t)row * 32 + d] = z;
            if (which) Zi_pack[(size_t)row * 32 + d] = (__bf16)z;
        } else {
            const int t2 = tid - 192;              // 8 rows x 8 pad slots
            const int r = t2 >> 3, k = 24 + (t2 & 7);
            const int row = rowbase + r;
            (which ? Zi_pad : Zj_pad)[(size_t)row * 32 + k] = 0.f;
            if (which) Zi_pack[(size_t)row * 32 + k] =
                (__bf16)((k == Dd) ? 1.f : 0.f);
        }
    } else if (bid < 2240) {
        const int rem = bid - 512;
        transpose_tile_v(Wv1, Wv1T, 3 * Hh, Oo, rem % 24, rem / 24, smem, tid);
    } else {
        const int rem = bid - 2240;
        transpose_tile_v(Wv2, Wv2T, Oo, Hh, rem % 24, rem / 24, smem, tid);
    }
}

// ---------------------------------------------------------------------------
// pair_kernel v3: B0/B1 fragments built per-lane in the preamble (bit-exact
// same fmaf/cvt order as the old prep_b) — kills prep_b dispatch + the
// 25 MB B0all round-trip. g<3 lanes: W1i + zj*W1h pack; g=3 lanes: inline
// rowadd (f32 Zj row is a uniform address -> broadcast loads).
// ---------------------------------------------------------------------------
__global__ __launch_bounds__(256, 4) void pair_kernel(
    const float* __restrict__ Zj_pad, const float* __restrict__ Zi_pad,
    const __bf16* __restrict__ Zi_pack,
    const float* __restrict__ Ws1, const float* __restrict__ bs1,
    const float* __restrict__ ws2, const float* __restrict__ bs2p,
    const int* __restrict__ mask, __bf16* __restrict__ probs)
{
    const int bp = blockIdx.x;
    const int b  = bp >> 9;              // S = 512
    const int tid  = threadIdx.x;
    const int lane = tid & 63;
    const int wid  = tid >> 6;
    const int col  = lane & 15;
    const int g    = lane >> 4;

    __shared__ float logitsl[Ss];
    __shared__ float red[8];

    // zj8 (f32, padded -> uniform across all lane groups; g=3 reads zeros)
    float zj8[8];
    {
        const float* zr = Zj_pad + (size_t)bp * 32 + g * 8;
        const float4 u = *(const float4*)zr;
        const float4 v = *(const float4*)(zr + 4);
        zj8[0]=u.x; zj8[1]=u.y; zj8[2]=u.z; zj8[3]=u.w;
        zj8[4]=v.x; zj8[5]=v.y; zj8[6]=v.z; zj8[7]=v.w;
    }

    // B fragments built in-register (was prep_b + B0all/B1g round trip)
    bf16x8 bw0[6], bw1[6];
    float ws2r[6];
    if (g < 3) {
        #pragma unroll
        for (int n = 0; n < 6; ++n) {
            const int m = n * 16 + col;
            ws2r[n] = ws2[m];
            bf16x8 b0, b1;
            #pragma unroll
            for (int j = 0; j < 8; ++j) {
                const int d = g * 8 + j;
                b0[j] = (__bf16)fmaf(zj8[j], Ws1[(2 * Dd + d) * Mm + m],
                                     Ws1[(Dd + d) * Mm + m]);
                b1[j] = (__bf16)Ws1[(3 * Dd + d) * Mm + m];
            }
            bw0[n] = b0; bw1[n] = b1;
        }
    } else {
        float zf[Dd];
        const float* zr = Zj_pad + (size_t)bp * 32;
        #pragma unroll
        for (int k = 0; k < 6; ++k) {
            const f32x4 v = *(const f32x4*)(zr + k * 4);
            zf[k * 4 + 0] = v[0]; zf[k * 4 + 1] = v[1];
            zf[k * 4 + 2] = v[2]; zf[k * 4 + 3] = v[3];
        }
        #pragma unroll
        for (int n = 0; n < 6; ++n) {
            const int m = n * 16 + col;
            ws2r[n] = ws2[m];
            float ra = bs1[m];
            #pragma unroll
            for (int d = 0; d < Dd; ++d) ra = fmaf(zf[d], Ws1[d * Mm + m], ra);
            bf16x8 b0, b1;
            #pragma unroll
            for (int j = 0; j < 8; ++j) { b0[j] = (__bf16)0.f; b1[j] = (__bf16)0.f; }
            b0[0] = (__bf16)ra;
            bw0[n] = b0; bw1[n] = b1;
        }
    }

    const float*  zipb = Zi_pad  + (size_t)b * Ss * 32;
    const __bf16* zpkb = Zi_pack + (size_t)b * Ss * 32;

    #pragma unroll 2
    for (int t = 0; t < 8; ++t) {
        const int q0 = wid * 128 + t * 16;
        const int q  = q0 + col;
        const bf16x8 a0 = *(const bf16x8*)(zpkb + (size_t)q * 32 + g * 8);
        const float4 u = *(const float4*)(zipb + (size_t)q * 32 + g * 8);
        const float4 v = *(const float4*)(zipb + (size_t)q * 32 + g * 8 + 4);
        bf16x8 a1;
        a1[0]=(__bf16)fabsf(zj8[0]-u.x); a1[1]=(__bf16)fabsf(zj8[1]-u.y);
        a1[2]=(__bf16)fabsf(zj8[2]-u.z); a1[3]=(__bf16)fabsf(zj8[3]-u.w);
        a1[4]=(__bf16)fabsf(zj8[4]-v.x); a1[5]=(__bf16)fabsf(zj8[5]-v.y);
        a1[6]=(__bf16)fabsf(zj8[6]-v.z); a1[7]=(__bf16)fabsf(zj8[7]-v.w);

        f32x4 acc[6];
        #pragma unroll
        for (int n = 0; n < 6; ++n) acc[n] = (f32x4){0.f, 0.f, 0.f, 0.f};
        #pragma unroll
        for (int n = 0; n < 6; ++n) {
            acc[n] = __builtin_amdgcn_mfma_f32_16x16x32_bf16(a0, bw0[n], acc[n], 0, 0, 0);
            acc[n] = __builtin_amdgcn_mfma_f32_16x16x32_bf16(a1, bw1[n], acc[n], 0, 0, 0);
        }

        float lsum[4] = {0.f, 0.f, 0.f, 0.f};
        #pragma unroll
        for (int n = 0; n < 6; ++n)
            #pragma unroll
            for (int r = 0; r < 4; ++r)
                lsum[r] = fmaf(fmaxf(acc[n][r], 0.f), ws2r[n], lsum[r]);
        #pragma unroll
        for (int off = 1; off <= 8; off <<= 1) {
            #pragma unroll
            for (int r = 0; r < 4; ++r) lsum[r] += __shfl_xor(lsum[r], off, 16);
        }
        if (col == 0) {
            float4 o = {lsum[0], lsum[1], lsum[2], lsum[3]};
            *(float4*)&logitsl[q0 + g * 4] = o;
        }
    }
    __syncthreads();

    const float bs2v = bs2p[0];
    const int* mrow = mask + (size_t)b * Ss;
    float l0 = logitsl[tid]       + bs2v + (1.0f - (float)mrow[tid])       * (-3.402823466e+38f);
    float l1 = logitsl[tid + 256] + bs2v + (1.0f - (float)mrow[tid + 256]) * (-3.402823466e+38f);
    float vmax = fmaxf(l0, l1);
    #pragma unroll
    for (int off = 32; off > 0; off >>= 1) vmax = fmaxf(vmax, __shfl_xor(vmax, off));
    if (lane == 0) red[wid] = vmax;
    __syncthreads();
    const float mx = fmaxf(fmaxf(red[0], red[1]), fmaxf(red[2], red[3]));
    const float e0 = __expf(l0 - mx);
    const float e1 = __expf(l1 - mx);
    float vs = e0 + e1;
    #pragma unroll
    for (int off = 32; off > 0; off >>= 1) vs += __shfl_xor(vs, off);
    if (lane == 0) red[4 + wid] = vs;
    __syncthreads();
    const float inv = 1.0f / (red[4] + red[5] + red[6] + red[7]);
    __bf16* prow = probs + (size_t)bp * Ss;
    prow[tid] = (__bf16)(e0 * inv);
    prow[tid + 256] = (__bf16)(e1 * inv);
}

// ---------------------------------------------------------------------------
// GEMM (unchanged): 64x96 tile, BK=64, global_load_lds(16B), triple-buffered
// LDS, counted vmcnt(5), both-sides XOR swizzle.
// ---------------------------------------------------------------------------
__device__ __forceinline__ void gload16(const __bf16* g, __bf16* l)
{
    __builtin_amdgcn_global_load_lds(
        (const __attribute__((address_space(1))) void*)g,
        (__attribute__((address_space(3))) void*)l, 16, 0, 0);
}

__device__ __forceinline__ int swz(int row, int k)
{
    return row * 64 + (k ^ ((row & 7) << 3));
}

template<int MODE>
__global__ __launch_bounds__(256) void gemm_kernel(
    const __bf16* __restrict__ A, const __bf16* __restrict__ Bt,
    const float* __restrict__ Hjf, const float* __restrict__ bias,
    const float* __restrict__ alphap,
    __bf16* __restrict__ obf, float* __restrict__ of)
{
    constexpr int K = (MODE == 0) ? 512 : (MODE == 1) ? 2304 : 768;
    constexpr int NIT = K / 64;

    __shared__ __align__(16) __bf16 As[3][64 * 64];   // 24 KB
    __shared__ __align__(16) __bf16 Bs[3][96 * 64];   // 36 KB

    const int tid = threadIdx.x;
    const int lane = tid & 63;
    const int wid = tid >> 6;
    const int col = lane & 15, g = lane >> 4;
    const int wm = wid >> 1, wn = wid & 1;     // 2x2 wave grid, wave = 32x48
    const int r0 = blockIdx.x * 64;
    const int n0 = blockIdx.y * 96;
    const __bf16* Btb = (MODE == 0) ? Bt + (size_t)(r0 >> 9) * (Hh * Ss) : Bt;

    const __bf16* asrc[2];
    const __bf16* bsrc[3];
    int aldo[2], bldo[3];
    #pragma unroll
    for (int i = 0; i < 2; ++i) {
        const int c = (wid * 2 + i) * 64 + lane;
        const int row = c >> 3;
        const int k16 = (c & 7) ^ (row & 7);
        asrc[i] = A + (size_t)(r0 + row) * K + k16 * 8;
        aldo[i] = (wid * 2 + i) * 512;
    }
    #pragma unroll
    for (int i = 0; i < 3; ++i) {
        const int c = (wid * 3 + i) * 64 + lane;
        const int row = c >> 3;
        const int k16 = (c & 7) ^ (row & 7);
        bsrc[i] = Btb + (size_t)(n0 + row) * K + k16 * 8;
        bldo[i] = (wid * 3 + i) * 512;
    }

    auto stage = [&](int t, int buf) {
        __bf16* ab = &As[buf][0];
        __bf16* bb = &Bs[buf][0];
        #pragma unroll
        for (int i = 0; i < 2; ++i) gload16(asrc[i] + (size_t)t * 64, ab + aldo[i]);
        #pragma unroll
        for (int i = 0; i < 3; ++i) gload16(bsrc[i] + (size_t)t * 64, bb + bldo[i]);
    };

    f32x4 acc[2][3];
    #pragma unroll
    for (int mi = 0; mi < 2; ++mi)
        #pragma unroll
        for (int ni = 0; ni < 3; ++ni) acc[mi][ni] = (f32x4){0.f, 0.f, 0.f, 0.f};

    stage(0, 0);
    stage(1, 1);

    for (int it = 0; it < NIT; ++it) {
        if (it < NIT - 1) asm volatile("s_waitcnt vmcnt(5)" ::: "memory");
        else              asm volatile("s_waitcnt vmcnt(0)" ::: "memory");
        __builtin_amdgcn_s_barrier();
        __builtin_amdgcn_sched_barrier(0);
        if (it + 2 < NIT) stage(it + 2, (it + 2) % 3);

        const __bf16* Ac = As[it % 3];
        const __bf16* Bc = Bs[it % 3];
        #pragma unroll
        for (int h = 0; h < 2; ++h) {
            const int ka = h * 32 + g * 8;
            const bf16x8 a0 = *(const bf16x8*)&Ac[swz(wm * 32 +      col, ka)];
            const bf16x8 a1 = *(const bf16x8*)&Ac[swz(wm * 32 + 16 + col, ka)];
            const bf16x8 b0 = *(const bf16x8*)&Bc[swz(wn * 48 +      col, ka)];
            const bf16x8 b1 = *(const bf16x8*)&Bc[swz(wn * 48 + 16 + col, ka)];
            const bf16x8 b2 = *(const bf16x8*)&Bc[swz(wn * 48 + 32 + col, ka)];
            acc[0][0] = __builtin_amdgcn_mfma_f32_16x16x32_bf16(a0, b0, acc[0][0], 0, 0, 0);
            acc[0][1] = __builtin_amdgcn_mfma_f32_16x16x32_bf16(a0, b1, acc[0][1], 0, 0, 0);
            acc[0][2] = __builtin_amdgcn_mfma_f32_16x16x32_bf16(a0, b2, acc[0][2], 0, 0, 0);
            acc[1][0] = __builtin_amdgcn_mfma_f32_16x16x32_bf16(a1, b0, acc[1][0], 0, 0, 0);
            acc[1][1] = __builtin_amdgcn_mfma_f32_16x16x32_bf16(a1, b1, acc[1][1], 0, 0, 0);
            acc[1][2] = __builtin_amdgcn_mfma_f32_16x16x32_bf16(a1, b2, acc[1][2], 0, 0, 0);
        }
    }

    const float al = (MODE == 2) ? alphap[0] : 0.f;
    #pragma unroll
    for (int mi = 0; mi < 2; ++mi) {
        #pragma unroll
        for (int r = 0; r < 4; ++r) {
            const int row = r0 + wm * 32 + mi * 16 + g * 4 + r;
            #pragma unroll
            for (int ni = 0; ni < 3; ++ni) {
                const int cn = n0 + wn * 48 + ni * 16 + col;
                const float v = acc[mi][ni][r];
                if (MODE == 0) {
                    const float hjv = Hjf[(size_t)row * Hh + cn];
                    obf[(size_t)row * 2304 + cn] = (__bf16)v;
                    obf[(size_t)row * 2304 + 1536 + cn] = (__bf16)(v * hjv);
                } else if (MODE == 1) {
                    obf[(size_t)row * Oo + cn] = (__bf16)fmaxf(v + bias[cn], 0.f);
                } else {
                    of[(size_t)row * Hh + cn] = al * (v + bias[cn]);
                }
            }
        }
    }
}

// ---------------------------------------------------------------------------
extern "C" void kernel_launch(void* const* d_in, const int* in_sizes, int n_in,
                              void* d_out, int out_size, void* d_ws, size_t ws_size,
                              hipStream_t stream)
{
    const float* Hj  = (const float*)d_in[0];
    const float* Hi  = (const float*)d_in[1];
    const float* Wpj = (const float*)d_in[2];
    const float* Wpi = (const float*)d_in[3];
    const float* Ws1 = (const float*)d_in[4];
    const float* bs1 = (const float*)d_in[5];
    const float* ws2 = (const float*)d_in[6];
    const float* bs2 = (const float*)d_in[7];
    const float* Wv1 = (const float*)d_in[8];
    const float* bv1 = (const float*)d_in[9];
    const float* Wv2 = (const float*)d_in[10];
    const float* bv2 = (const float*)d_in[11];
    const float* alpha = (const float*)d_in[12];
    const int* mask  = (const int*)d_in[13];

    // workspace (float units) — all regions DISTINCT
    float* ws = (float*)d_ws;
    float* Zj_pad  = ws;                  // 65536   [2048][32] f32
    float* Zi_pad  = Zj_pad + 65536;      // 65536   [2048][32] f32
    float* Zpack_f = Zi_pad + 65536;      // 32768   [2048][32] bf16
    float* probs_f = Zpack_f + 32768;     // 524288
    float* HiT_f   = probs_f + 524288;    // 786432
    float* Wv2T_f  = HiT_f + 786432;      // 294912
    float* mhid_f  = Wv2T_f + 294912;     // 786432
    float* Acat_f  = mhid_f + 786432;     // 2359296
    float* Wv1T_f  = Acat_f + 2359296;    // 884736
    // total ≈ 5.80M floats = 23.2 MB

    __bf16* Zi_pack  = (__bf16*)Zpack_f;  // [2048][32]
    __bf16* probs_bf = (__bf16*)probs_f;  // [2048][512]
    __bf16* HiT      = (__bf16*)HiT_f;    // [4][768][512]
    __bf16* Wv2T     = (__bf16*)Wv2T_f;   // [768][768]
    __bf16* mhid_bf  = (__bf16*)mhid_f;   // [2048][768]
    __bf16* Acat     = (__bf16*)Acat_f;   // [2048][2304]
    __bf16* Wv1T     = (__bf16*)Wv1T_f;   // [768][2304]

    prep_a<<<dim3(2816), 256, 0, stream>>>(
        Hj, Hi, Wpj, Wpi, Wv1, Wv2,
        Zj_pad, Zi_pad, Zi_pack, HiT, Wv1T, Wv2T, Acat);
    pair_kernel<<<dim3(Bb * Ss), 256, 0, stream>>>(
        Zj_pad, Zi_pad, Zi_pack, Ws1, bs1, ws2, bs2, mask, probs_bf);
    gemm_kernel<0><<<dim3(2048 / 64, Hh / 96), 256, 0, stream>>>(
        probs_bf, HiT, Hj, nullptr, nullptr, Acat, nullptr);
    gemm_kernel<1><<<dim3(2048 / 64, Oo / 96), 256, 0, stream>>>(
        Acat, Wv1T, nullptr, bv1, nullptr, mhid_bf, nullptr);
    gemm_kernel<2><<<dim3(2048 / 64, Hh / 96), 256, 0, stream>>>(
        mhid_bf, Wv2T, nullptr, bv2, alpha, nullptr, (float*)d_out);
}

// Round 5
// 185.169 us; speedup vs baseline: 1.0470x; 1.0470x over previous
//
#include <hip/hip_runtime.h>
#include <hip/hip_bf16.h>

#define Bb 4
#define Ss 512
#define Hh 768
#define Dd 24
#define Mm 96
#define Oo 768

typedef __bf16 bf16x8 __attribute__((ext_vector_type(8)));
typedef __bf16 bf16x4 __attribute__((ext_vector_type(4)));
typedef float f32x4 __attribute__((ext_vector_type(4)));

// ---------------------------------------------------------------------------
// Transpose tile: dst[c][r] = bf16(src[r][c]), one 32x32 tile, 8B stores.
// ---------------------------------------------------------------------------
__device__ __forceinline__ void transpose_tile_v(
    const float* __restrict__ s, __bf16* __restrict__ d,
    int R, int C, int bx, int by, float* smem, int tid)
{
    // smem used as t[32][33]
    const int x = tid & 31, y = tid >> 5;
    const int c0 = bx * 32, r0 = by * 32;
    #pragma unroll
    for (int i = 0; i < 4; ++i)
        smem[(y + 8 * i) * 33 + x] = s[(size_t)(r0 + y + 8 * i) * C + c0 + x];
    __syncthreads();
    const int cl = tid >> 3, rg = tid & 7;     // 32 cols x 8 row-groups
    bf16x4 o = { (__bf16)smem[(rg * 4 + 0) * 33 + cl],
                 (__bf16)smem[(rg * 4 + 1) * 33 + cl],
                 (__bf16)smem[(rg * 4 + 2) * 33 + cl],
                 (__bf16)smem[(rg * 4 + 3) * 33 + cl] };
    *(bf16x4*)&d[(size_t)(c0 + cl) * R + r0 + rg * 4] = o;
}

// ---------------------------------------------------------------------------
// prep_a (unchanged from R4): proj + transposes + packs.
// ---------------------------------------------------------------------------
__global__ __launch_bounds__(256) void prep_a(
    const float* __restrict__ Hj, const float* __restrict__ Hi,
    const float* __restrict__ Wpj, const float* __restrict__ Wpi,
    const float* __restrict__ Wv1, const float* __restrict__ Wv2,
    float* __restrict__ Zj_pad, float* __restrict__ Zi_pad,
    __bf16* __restrict__ Zi_pack,
    __bf16* __restrict__ HiT, __bf16* __restrict__ Wv1T,
    __bf16* __restrict__ Wv2T, __bf16* __restrict__ Acat)
{
    __shared__ float smem[7744];   // proj: rowbuf 6144 + partial [8][8][25]
    const int bid = blockIdx.x;
    const int tid = threadIdx.x;

    if (bid < 512) {
        const int which = bid >> 8;               // 0 = j, 1 = i
        const int rowbase = (bid & 255) * 8;
        const float* src = (which ? Hi : Hj) + (size_t)rowbase * Hh;
        const float* W = which ? Wpi : Wpj;
        f32x4* rowbuf4 = (f32x4*)smem;            // [1536] = 8 rows x 192
        float* partial = smem + 6144;             // [8][8][25]

        #pragma unroll
        for (int k2 = 0; k2 < 6; ++k2) {
            const int f = tid + 256 * k2;
            rowbuf4[f] = ((const f32x4*)src)[f];
        }
        __syncthreads();

        if (which == 0) {
            #pragma unroll
            for (int k2 = 0; k2 < 6; ++k2) {
                const int f = tid + 256 * k2;
                const int r = f / 192, kk = f % 192;
                const f32x4 v = rowbuf4[f];
                bf16x4 o = {(__bf16)v[0], (__bf16)v[1], (__bf16)v[2], (__bf16)v[3]};
                *(bf16x4*)&Acat[(size_t)(rowbase + r) * 2304 + Hh + kk * 4] = o;
            }
        } else {
            const int bz = rowbase >> 9, q0 = rowbase & 511;
            __bf16* hb = HiT + (size_t)bz * Hh * Ss + q0;
            #pragma unroll
            for (int k2 = 0; k2 < 3; ++k2) {
                const int h = tid + 256 * k2;
                bf16x8 o;
                #pragma unroll
                for (int r = 0; r < 8; ++r) o[r] = (__bf16)smem[r * Hh + h];
                *(bf16x8*)&hb[(size_t)h * Ss] = o;
            }
        }

        if (tid < 192) {
            const int d = tid % Dd, e = tid / Dd;
            float acc[8];
            #pragma unroll
            for (int r = 0; r < 8; ++r) acc[r] = 0.f;
            const float* Wb = W + (size_t)(e * 96) * Dd + d;
            const f32x4* rb = rowbuf4 + e * 24;
            #pragma unroll 4
            for (int h4 = 0; h4 < 24; ++h4) {
                const float w0 = Wb[(h4 * 4 + 0) * Dd];
                const float w1 = Wb[(h4 * 4 + 1) * Dd];
                const float w2 = Wb[(h4 * 4 + 2) * Dd];
                const float w3 = Wb[(h4 * 4 + 3) * Dd];
                #pragma unroll
                for (int r = 0; r < 8; ++r) {
                    const f32x4 v = rb[r * 192 + h4];
                    acc[r] = fmaf(v[0], w0, acc[r]);
                    acc[r] = fmaf(v[1], w1, acc[r]);
                    acc[r] = fmaf(v[2], w2, acc[r]);
                    acc[r] = fmaf(v[3], w3, acc[r]);
                }
            }
            #pragma unroll
            for (int r = 0; r < 8; ++r) partial[e * 200 + r * 25 + d] = acc[r];
        }
        __syncthreads();
        if (tid < 192) {
            const int r = tid / Dd, d = tid % Dd;
            float z = 0.f;
            #pragma unroll
            for (int e = 0; e < 8; ++e) z += partial[e * 200 + r * 25 + d];
            const int row = rowbase + r;
            (which ? Zi_pad : Zj_pad)[(size_t)row * 32 + d] = z;
            if (which) Zi_pack[(size_t)row * 32 + d] = (__bf16)z;
        } else {
            const int t2 = tid - 192;              // 8 rows x 8 pad slots
            const int r = t2 >> 3, k = 24 + (t2 & 7);
            const int row = rowbase + r;
            (which ? Zi_pad : Zj_pad)[(size_t)row * 32 + k] = 0.f;
            if (which) Zi_pack[(size_t)row * 32 + k] =
                (__bf16)((k == Dd) ? 1.f : 0.f);
        }
    } else if (bid < 2240) {
        const int rem = bid - 512;
        transpose_tile_v(Wv1, Wv1T, 3 * Hh, Oo, rem % 24, rem / 24, smem, tid);
    } else {
        const int rem = bid - 2240;
        transpose_tile_v(Wv2, Wv2T, Oo, Hh, rem % 24, rem / 24, smem, tid);
    }
}

// ---------------------------------------------------------------------------
// pair_kernel v4: 128-thread blocks, 2 waves share one p, each wave owns a
// 256-q half (16 t-iters). Halves the redundant B-fragment preamble (was x4),
// doubles per-wave loop depth, raises occupancy to 4 waves/SIMD. t-loop math
// bit-identical to v3.
// ---------------------------------------------------------------------------
__global__ __launch_bounds__(128, 4) void pair_kernel(
    const float* __restrict__ Zj_pad, const float* __restrict__ Zi_pad,
    const __bf16* __restrict__ Zi_pack,
    const float* __restrict__ Ws1, const float* __restrict__ bs1,
    const float* __restrict__ ws2, const float* __restrict__ bs2p,
    const int* __restrict__ mask, __bf16* __restrict__ probs)
{
    const int bp = blockIdx.x;           // [0, 2048) = (b,p)
    const int b  = bp >> 9;              // S = 512
    const int tid  = threadIdx.x;        // [0, 128)
    const int lane = tid & 63;
    const int wid  = tid >> 6;           // 0..1 (q-half)
    const int col  = lane & 15;
    const int g    = lane >> 4;

    __shared__ float logitsl[Ss];
    __shared__ float red[4];

    // zj8 (f32, padded -> uniform across all lane groups; g=3 reads zeros)
    float zj8[8];
    {
        const float* zr = Zj_pad + (size_t)bp * 32 + g * 8;
        const float4 u = *(const float4*)zr;
        const float4 v = *(const float4*)(zr + 4);
        zj8[0]=u.x; zj8[1]=u.y; zj8[2]=u.z; zj8[3]=u.w;
        zj8[4]=v.x; zj8[5]=v.y; zj8[6]=v.z; zj8[7]=v.w;
    }

    // B fragments in-register (per wave; x2 redundant, was x4)
    bf16x8 bw0[6], bw1[6];
    float ws2r[6];
    if (g < 3) {
        #pragma unroll
        for (int n = 0; n < 6; ++n) {
            const int m = n * 16 + col;
            ws2r[n] = ws2[m];
            bf16x8 b0, b1;
            #pragma unroll
            for (int j = 0; j < 8; ++j) {
                const int d = g * 8 + j;
                b0[j] = (__bf16)fmaf(zj8[j], Ws1[(2 * Dd + d) * Mm + m],
                                     Ws1[(Dd + d) * Mm + m]);
                b1[j] = (__bf16)Ws1[(3 * Dd + d) * Mm + m];
            }
            bw0[n] = b0; bw1[n] = b1;
        }
    } else {
        float zf[Dd];
        const float* zr = Zj_pad + (size_t)bp * 32;
        #pragma unroll
        for (int k = 0; k < 6; ++k) {
            const f32x4 v = *(const f32x4*)(zr + k * 4);
            zf[k * 4 + 0] = v[0]; zf[k * 4 + 1] = v[1];
            zf[k * 4 + 2] = v[2]; zf[k * 4 + 3] = v[3];
        }
        #pragma unroll
        for (int n = 0; n < 6; ++n) {
            const int m = n * 16 + col;
            ws2r[n] = ws2[m];
            float ra = bs1[m];
            #pragma unroll
            for (int d = 0; d < Dd; ++d) ra = fmaf(zf[d], Ws1[d * Mm + m], ra);
            bf16x8 b0, b1;
            #pragma unroll
            for (int j = 0; j < 8; ++j) { b0[j] = (__bf16)0.f; b1[j] = (__bf16)0.f; }
            b0[0] = (__bf16)ra;
            bw0[n] = b0; bw1[n] = b1;
        }
    }

    const float*  zipb = Zi_pad  + (size_t)b * Ss * 32;
    const __bf16* zpkb = Zi_pack + (size_t)b * Ss * 32;

    #pragma unroll 2
    for (int t = 0; t < 16; ++t) {
        const int q0 = wid * 256 + t * 16;
        const int q  = q0 + col;
        const bf16x8 a0 = *(const bf16x8*)(zpkb + (size_t)q * 32 + g * 8);
        const float4 u = *(const float4*)(zipb + (size_t)q * 32 + g * 8);
        const float4 v = *(const float4*)(zipb + (size_t)q * 32 + g * 8 + 4);
        bf16x8 a1;
        a1[0]=(__bf16)fabsf(zj8[0]-u.x); a1[1]=(__bf16)fabsf(zj8[1]-u.y);
        a1[2]=(__bf16)fabsf(zj8[2]-u.z); a1[3]=(__bf16)fabsf(zj8[3]-u.w);
        a1[4]=(__bf16)fabsf(zj8[4]-v.x); a1[5]=(__bf16)fabsf(zj8[5]-v.y);
        a1[6]=(__bf16)fabsf(zj8[6]-v.z); a1[7]=(__bf16)fabsf(zj8[7]-v.w);

        f32x4 acc[6];
        #pragma unroll
        for (int n = 0; n < 6; ++n) acc[n] = (f32x4){0.f, 0.f, 0.f, 0.f};
        #pragma unroll
        for (int n = 0; n < 6; ++n) {
            acc[n] = __builtin_amdgcn_mfma_f32_16x16x32_bf16(a0, bw0[n], acc[n], 0, 0, 0);
            acc[n] = __builtin_amdgcn_mfma_f32_16x16x32_bf16(a1, bw1[n], acc[n], 0, 0, 0);
        }

        float lsum[4] = {0.f, 0.f, 0.f, 0.f};
        #pragma unroll
        for (int n = 0; n < 6; ++n)
            #pragma unroll
            for (int r = 0; r < 4; ++r)
                lsum[r] = fmaf(fmaxf(acc[n][r], 0.f), ws2r[n], lsum[r]);
        #pragma unroll
        for (int off = 1; off <= 8; off <<= 1) {
            #pragma unroll
            for (int r = 0; r < 4; ++r) lsum[r] += __shfl_xor(lsum[r], off, 16);
        }
        if (col == 0) {
            float4 o = {lsum[0], lsum[1], lsum[2], lsum[3]};
            *(float4*)&logitsl[q0 + g * 4] = o;
        }
    }
    __syncthreads();

    // softmax: 128 threads x 4 q, vectorized
    const float bs2v = bs2p[0];
    const int* mrow = mask + (size_t)b * Ss;
    const int q4 = tid * 4;
    const float4 lv = *(const float4*)&logitsl[q4];
    const int4  mv = *(const int4*)&mrow[q4];
    float l0 = lv.x + bs2v + (1.0f - (float)mv.x) * (-3.402823466e+38f);
    float l1 = lv.y + bs2v + (1.0f - (float)mv.y) * (-3.402823466e+38f);
    float l2 = lv.z + bs2v + (1.0f - (float)mv.z) * (-3.402823466e+38f);
    float l3 = lv.w + bs2v + (1.0f - (float)mv.w) * (-3.402823466e+38f);
    float vmax = fmaxf(fmaxf(l0, l1), fmaxf(l2, l3));
    #pragma unroll
    for (int off = 32; off > 0; off >>= 1) vmax = fmaxf(vmax, __shfl_xor(vmax, off));
    if (lane == 0) red[wid] = vmax;
    __syncthreads();
    const float mx = fmaxf(red[0], red[1]);
    const float e0 = __expf(l0 - mx);
    const float e1 = __expf(l1 - mx);
    const float e2 = __expf(l2 - mx);
    const float e3 = __expf(l3 - mx);
    float vs = (e0 + e1) + (e2 + e3);
    #pragma unroll
    for (int off = 32; off > 0; off >>= 1) vs += __shfl_xor(vs, off);
    if (lane == 0) red[2 + wid] = vs;
    __syncthreads();
    const float inv = 1.0f / (red[2] + red[3]);
    bf16x4 o = { (__bf16)(e0 * inv), (__bf16)(e1 * inv),
                 (__bf16)(e2 * inv), (__bf16)(e3 * inv) };
    *(bf16x4*)&probs[(size_t)bp * Ss + q4] = o;
}

// ---------------------------------------------------------------------------
// GEMM (unchanged): 64x96 tile, BK=64, global_load_lds(16B), triple-buffered
// LDS, counted vmcnt(5), both-sides XOR swizzle.
// ---------------------------------------------------------------------------
__device__ __forceinline__ void gload16(const __bf16* g, __bf16* l)
{
    __builtin_amdgcn_global_load_lds(
        (const __attribute__((address_space(1))) void*)g,
        (__attribute__((address_space(3))) void*)l, 16, 0, 0);
}

__device__ __forceinline__ int swz(int row, int k)
{
    return row * 64 + (k ^ ((row & 7) << 3));
}

template<int MODE>
__global__ __launch_bounds__(256) void gemm_kernel(
    const __bf16* __restrict__ A, const __bf16* __restrict__ Bt,
    const float* __restrict__ Hjf, const float* __restrict__ bias,
    const float* __restrict__ alphap,
    __bf16* __restrict__ obf, float* __restrict__ of)
{
    constexpr int K = (MODE == 0) ? 512 : (MODE == 1) ? 2304 : 768;
    constexpr int NIT = K / 64;

    __shared__ __align__(16) __bf16 As[3][64 * 64];   // 24 KB
    __shared__ __align__(16) __bf16 Bs[3][96 * 64];   // 36 KB

    const int tid = threadIdx.x;
    const int lane = tid & 63;
    const int wid = tid >> 6;
    const int col = lane & 15, g = lane >> 4;
    const int wm = wid >> 1, wn = wid & 1;     // 2x2 wave grid, wave = 32x48
    const int r0 = blockIdx.x * 64;
    const int n0 = blockIdx.y * 96;
    const __bf16* Btb = (MODE == 0) ? Bt + (size_t)(r0 >> 9) * (Hh * Ss) : Bt;

    const __bf16* asrc[2];
    const __bf16* bsrc[3];
    int aldo[2], bldo[3];
    #pragma unroll
    for (int i = 0; i < 2; ++i) {
        const int c = (wid * 2 + i) * 64 + lane;
        const int row = c >> 3;
        const int k16 = (c & 7) ^ (row & 7);
        asrc[i] = A + (size_t)(r0 + row) * K + k16 * 8;
        aldo[i] = (wid * 2 + i) * 512;
    }
    #pragma unroll
    for (int i = 0; i < 3; ++i) {
        const int c = (wid * 3 + i) * 64 + lane;
        const int row = c >> 3;
        const int k16 = (c & 7) ^ (row & 7);
        bsrc[i] = Btb + (size_t)(n0 + row) * K + k16 * 8;
        bldo[i] = (wid * 3 + i) * 512;
    }

    auto stage = [&](int t, int buf) {
        __bf16* ab = &As[buf][0];
        __bf16* bb = &Bs[buf][0];
        #pragma unroll
        for (int i = 0; i < 2; ++i) gload16(asrc[i] + (size_t)t * 64, ab + aldo[i]);
        #pragma unroll
        for (int i = 0; i < 3; ++i) gload16(bsrc[i] + (size_t)t * 64, bb + bldo[i]);
    };

    f32x4 acc[2][3];
    #pragma unroll
    for (int mi = 0; mi < 2; ++mi)
        #pragma unroll
        for (int ni = 0; ni < 3; ++ni) acc[mi][ni] = (f32x4){0.f, 0.f, 0.f, 0.f};

    stage(0, 0);
    stage(1, 1);

    for (int it = 0; it < NIT; ++it) {
        if (it < NIT - 1) asm volatile("s_waitcnt vmcnt(5)" ::: "memory");
        else              asm volatile("s_waitcnt vmcnt(0)" ::: "memory");
        __builtin_amdgcn_s_barrier();
        __builtin_amdgcn_sched_barrier(0);
        if (it + 2 < NIT) stage(it + 2, (it + 2) % 3);

        const __bf16* Ac = As[it % 3];
        const __bf16* Bc = Bs[it % 3];
        #pragma unroll
        for (int h = 0; h < 2; ++h) {
            const int ka = h * 32 + g * 8;
            const bf16x8 a0 = *(const bf16x8*)&Ac[swz(wm * 32 +      col, ka)];
            const bf16x8 a1 = *(const bf16x8*)&Ac[swz(wm * 32 + 16 + col, ka)];
            const bf16x8 b0 = *(const bf16x8*)&Bc[swz(wn * 48 +      col, ka)];
            const bf16x8 b1 = *(const bf16x8*)&Bc[swz(wn * 48 + 16 + col, ka)];
            const bf16x8 b2 = *(const bf16x8*)&Bc[swz(wn * 48 + 32 + col, ka)];
            acc[0][0] = __builtin_amdgcn_mfma_f32_16x16x32_bf16(a0, b0, acc[0][0], 0, 0, 0);
            acc[0][1] = __builtin_amdgcn_mfma_f32_16x16x32_bf16(a0, b1, acc[0][1], 0, 0, 0);
            acc[0][2] = __builtin_amdgcn_mfma_f32_16x16x32_bf16(a0, b2, acc[0][2], 0, 0, 0);
            acc[1][0] = __builtin_amdgcn_mfma_f32_16x16x32_bf16(a1, b0, acc[1][0], 0, 0, 0);
            acc[1][1] = __builtin_amdgcn_mfma_f32_16x16x32_bf16(a1, b1, acc[1][1], 0, 0, 0);
            acc[1][2] = __builtin_amdgcn_mfma_f32_16x16x32_bf16(a1, b2, acc[1][2], 0, 0, 0);
        }
    }

    const float al = (MODE == 2) ? alphap[0] : 0.f;
    #pragma unroll
    for (int mi = 0; mi < 2; ++mi) {
        #pragma unroll
        for (int r = 0; r < 4; ++r) {
            const int row = r0 + wm * 32 + mi * 16 + g * 4 + r;
            #pragma unroll
            for (int ni = 0; ni < 3; ++ni) {
                const int cn = n0 + wn * 48 + ni * 16 + col;
                const float v = acc[mi][ni][r];
                if (MODE == 0) {
                    const float hjv = Hjf[(size_t)row * Hh + cn];
                    obf[(size_t)row * 2304 + cn] = (__bf16)v;
                    obf[(size_t)row * 2304 + 1536 + cn] = (__bf16)(v * hjv);
                } else if (MODE == 1) {
                    obf[(size_t)row * Oo + cn] = (__bf16)fmaxf(v + bias[cn], 0.f);
                } else {
                    of[(size_t)row * Hh + cn] = al * (v + bias[cn]);
                }
            }
        }
    }
}

// ---------------------------------------------------------------------------
extern "C" void kernel_launch(void* const* d_in, const int* in_sizes, int n_in,
                              void* d_out, int out_size, void* d_ws, size_t ws_size,
                              hipStream_t stream)
{
    const float* Hj  = (const float*)d_in[0];
    const float* Hi  = (const float*)d_in[1];
    const float* Wpj = (const float*)d_in[2];
    const float* Wpi = (const float*)d_in[3];
    const float* Ws1 = (const float*)d_in[4];
    const float* bs1 = (const float*)d_in[5];
    const float* ws2 = (const float*)d_in[6];
    const float* bs2 = (const float*)d_in[7];
    const float* Wv1 = (const float*)d_in[8];
    const float* bv1 = (const float*)d_in[9];
    const float* Wv2 = (const float*)d_in[10];
    const float* bv2 = (const float*)d_in[11];
    const float* alpha = (const float*)d_in[12];
    const int* mask  = (const int*)d_in[13];

    // workspace (float units) — all regions DISTINCT
    float* ws = (float*)d_ws;
    float* Zj_pad  = ws;                  // 65536   [2048][32] f32
    float* Zi_pad  = Zj_pad + 65536;      // 65536   [2048][32] f32
    float* Zpack_f = Zi_pad + 65536;      // 32768   [2048][32] bf16
    float* probs_f = Zpack_f + 32768;     // 524288
    float* HiT_f   = probs_f + 524288;    // 786432
    float* Wv2T_f  = HiT_f + 786432;      // 294912
    float* mhid_f  = Wv2T_f + 294912;     // 786432
    float* Acat_f  = mhid_f + 786432;     // 2359296
    float* Wv1T_f  = Acat_f + 2359296;    // 884736
    // total ≈ 5.80M floats = 23.2 MB

    __bf16* Zi_pack  = (__bf16*)Zpack_f;  // [2048][32]
    __bf16* probs_bf = (__bf16*)probs_f;  // [2048][512]
    __bf16* HiT      = (__bf16*)HiT_f;    // [4][768][512]
    __bf16* Wv2T     = (__bf16*)Wv2T_f;   // [768][768]
    __bf16* mhid_bf  = (__bf16*)mhid_f;   // [2048][768]
    __bf16* Acat     = (__bf16*)Acat_f;   // [2048][2304]
    __bf16* Wv1T     = (__bf16*)Wv1T_f;   // [768][2304]

    prep_a<<<dim3(2816), 256, 0, stream>>>(
        Hj, Hi, Wpj, Wpi, Wv1, Wv2,
        Zj_pad, Zi_pad, Zi_pack, HiT, Wv1T, Wv2T, Acat);
    pair_kernel<<<dim3(Bb * Ss), 128, 0, stream>>>(
        Zj_pad, Zi_pad, Zi_pack, Ws1, bs1, ws2, bs2, mask, probs_bf);
    gemm_kernel<0><<<dim3(2048 / 64, Hh / 96), 256, 0, stream>>>(
        probs_bf, HiT, Hj, nullptr, nullptr, Acat, nullptr);
    gemm_kernel<1><<<dim3(2048 / 64, Oo / 96), 256, 0, stream>>>(
        Acat, Wv1T, nullptr, bv1, nullptr, mhid_bf, nullptr);
    gemm_kernel<2><<<dim3(2048 / 64, Hh / 96), 256, 0, stream>>>(
        mhid_bf, Wv2T, nullptr, bv2, alpha, nullptr, (float*)d_out);
}